// Round 12
// baseline (19.602 us; speedup 1.0000x reference)
//
#include <hip/hip_runtime.h>
#include <math.h>

// Problem constants (from reference)
#define BB 16
#define CC 3
#define OO 32
#define HH 128
#define WW 128
#define OH 124
#define OW 124
#define NPIX (OH * OW)          // 15376
#define NG   (NPIX / 4)         // 3844 4-pixel groups
#define GW   (OW / 4)           // 31 groups per output row
#define KF 25.0f

#define TPB  256
#define NBLK (NG / 2)           // 1922 blocks, 8 pixels each -> 30 waves/CU

#if defined(__has_builtin)
#if __has_builtin(__builtin_amdgcn_sqrtf)
#define FSQRT(x) __builtin_amdgcn_sqrtf(x)
#else
#define FSQRT(x) sqrtf(x)
#endif
#else
#define FSQRT(x) sqrtf(x)
#endif

// exp(-0.5 z^2) = exp2(-(z*K2)^2), K2 = sqrt(0.5/ln2), folded into invstd
#define K2EXP 0.84932180f

// ---------------------------------------------------------------------------
// ONE kernel. Block owns 8 pixels (2 pix4 groups) x all (16 b, 32 o).
//   t = b*16 + og*2 + p4   (b: 0..15, og: 0..7 -> 4 o each, p4: 0..1)
// Phase 0: window sums from x -> LDS           (96 threads; t<96 also preload W)
// Phase 1: dist partials, dist[4][4] in VGPRs  (256 threads, 48 sqrt each)
// Phase 2: per-pixel unbiased 1/std (double)   (32 + 8 threads)
// Phase 3: out = exp2(-(d*isd')^2)             (256 threads, f4 stores)
// 2x the wave-residency of every prior round (30 waves/CU vs 15), same
// total loads/sqrt/stores. Bijective XCD swizzle (1922 = 2*241 + 6*240).
// ---------------------------------------------------------------------------
__global__ __launch_bounds__(TPB, 8)
void fused_one(const float* __restrict__ x,
               const float* __restrict__ wgt,
               float* __restrict__ out) {
    __shared__ float  sS1[BB * CC][9];     // 1.7 KB
    __shared__ float  sS2[BB * CC][9];     // 1.7 KB
    __shared__ float  sPS[BB * 8][9];      // 4.6 KB  row = b*8+og
    __shared__ float  sPQ[BB * 8][9];      // 4.6 KB
    __shared__ float  sW[OO * CC];
    __shared__ float  sInv[8];
    __shared__ double sRm[8][4];
    __shared__ double sRq[8][4];

    const int t = threadIdx.x;

    // Bijective XCD swizzle: 1922 = 2*241 + 6*240 (xcd 0,1 get 241 chunks).
    const int orig = blockIdx.x;
    const int xcd  = orig & 7;
    const int loc  = orig >> 3;
    const int chunk = ((xcd < 2) ? xcd * 241 : 2 * 241 + (xcd - 2) * 240) + loc;
    const int g0 = chunk * 2;              // first pix4 group (2 per block)

    // ---------------- Phase 0: weights + window sums ----------------
    if (t < OO * CC) sW[t] = wgt[t];       // 96 weights
    if (t < BB * CC * 2) {                 // 96 active
        int bc = t >> 1;                   // 0..47
        int p4 = t & 1;                    // 0..1
        int g  = g0 + p4;                  // < 3844 always (3844 = 1922*2)
        int i  = g / GW;
        int j0 = (g % GW) * 4;
        const float* img = x + (size_t)bc * (HH * WW);
        float S1[4] = {0, 0, 0, 0}, S2[4] = {0, 0, 0, 0};
#pragma unroll
        for (int di = 0; di < 5; ++di) {
            const float4* rp = reinterpret_cast<const float4*>(img + (i + di) * WW + j0);
            float4 lo = rp[0], hi = rp[1];
            float v[8] = {lo.x, lo.y, lo.z, lo.w, hi.x, hi.y, hi.z, hi.w};
            float q[8];
#pragma unroll
            for (int k = 0; k < 8; ++k) q[k] = v[k] * v[k];
            float r  = v[0] + v[1] + v[2] + v[3] + v[4];
            float rq = q[0] + q[1] + q[2] + q[3] + q[4];
            S1[0] += r;  S2[0] += rq;
#pragma unroll
            for (int u = 1; u < 4; ++u) {
                r  += v[u + 4] - v[u - 1];
                rq += q[u + 4] - q[u - 1];
                S1[u] += r;  S2[u] += rq;
            }
        }
#pragma unroll
        for (int u = 0; u < 4; ++u) {
            sS1[bc][p4 * 4 + u] = S1[u];
            sS2[bc][p4 * 4 + u] = S2[u];
        }
    }
    __syncthreads();

    // ---------------- Phase 1: dist partials (dist stays in registers) ----
    const int b  = t >> 4;        // 0..15
    const int og = (t >> 1) & 7;  // 0..7  (4 o's each)
    const int p4 = t & 1;         // 0..1  (4 pixels each)

    float S1c[CC][4], S2c[CC][4];
#pragma unroll
    for (int c = 0; c < CC; ++c) {
#pragma unroll
        for (int u = 0; u < 4; ++u) {
            S1c[c][u] = sS1[b * CC + c][p4 * 4 + u];
            S2c[c][u] = sS2[b * CC + c][p4 * 4 + u];
        }
    }

    float dist[4][4];
    float sum[4] = {0, 0, 0, 0}, sq[4] = {0, 0, 0, 0};
#pragma unroll
    for (int oo = 0; oo < 4; ++oo) {
        int o = og * 4 + oo;
        float d[4] = {0, 0, 0, 0};
#pragma unroll
        for (int c = 0; c < CC; ++c) {
            float w  = sW[o * CC + c];
            float tw = 2.0f * w;
            float kw = KF * w * w;
#pragma unroll
            for (int u = 0; u < 4; ++u) {
                float inner = S2c[c][u] - tw * S1c[c][u] + kw;
                d[u] += FSQRT(fmaxf(inner, 0.0f));
            }
        }
#pragma unroll
        for (int u = 0; u < 4; ++u) {
            dist[oo][u] = d[u];
            sum[u] += d[u];
            sq[u]  += d[u] * d[u];
        }
    }
#pragma unroll
    for (int u = 0; u < 4; ++u) {
        sPS[b * 8 + og][p4 * 4 + u] = sum[u];
        sPQ[b * 8 + og][p4 * 4 + u] = sq[u];
    }
    __syncthreads();

    // ---------------- Phase 2: per-pixel 1/std (double) ----------------
    if (t < 32) {
        int pix = t >> 2;   // 0..7
        int seg = t & 3;    // 0..3, 32 rows each
        double sm = 0.0, sQ = 0.0;
#pragma unroll
        for (int k = 0; k < 32; ++k) {
            sm += (double)sPS[seg * 32 + k][pix];
            sQ += (double)sPQ[seg * 32 + k][pix];
        }
        sRm[pix][seg] = sm;
        sRq[pix][seg] = sQ;
    }
    __syncthreads();
    if (t < 8) {
        double sm = sRm[t][0] + sRm[t][1] + sRm[t][2] + sRm[t][3];
        double sQ = sRq[t][0] + sRq[t][1] + sRq[t][2] + sRq[t][3];
        const double n = (double)(BB * OO);
        double mean = sm / n;
        double var = (sQ - n * mean * mean) / (n - 1.0);
        if (var < 0.0) var = 0.0;
        // fold exp constant: exp(-0.5 z^2) = exp2(-(z*K2EXP)^2)
        sInv[t] = (float)(K2EXP / sqrt(var));
    }
    __syncthreads();

    // ---------------- Phase 3: output ----------------
    float isd[4];
#pragma unroll
    for (int u = 0; u < 4; ++u) isd[u] = sInv[p4 * 4 + u];
    const size_t pixbase = (size_t)(g0 + p4) * 4;

#pragma unroll
    for (int oo = 0; oo < 4; ++oo) {
        int o = og * 4 + oo;
        float4 r;
        float z0 = dist[oo][0] * isd[0]; r.x = exp2f(-(z0 * z0));
        float z1 = dist[oo][1] * isd[1]; r.y = exp2f(-(z1 * z1));
        float z2 = dist[oo][2] * isd[2]; r.z = exp2f(-(z2 * z2));
        float z3 = dist[oo][3] * isd[3]; r.w = exp2f(-(z3 * z3));
        *reinterpret_cast<float4*>(&out[(size_t)(b * OO + o) * NPIX + pixbase]) = r;
    }
}

// ---------------------------------------------------------------------------
extern "C" void kernel_launch(void* const* d_in, const int* in_sizes, int n_in,
                              void* d_out, int out_size, void* d_ws, size_t ws_size,
                              hipStream_t stream) {
    const float* x   = (const float*)d_in[0];   // (16,3,128,128)
    const float* wgt = (const float*)d_in[1];   // (32,3)
    float* out = (float*)d_out;                 // (16,32,124,124)

    fused_one<<<NBLK, TPB, 0, stream>>>(x, wgt, out);
}

// Round 13
// 19.219 us; speedup vs baseline: 1.0199x; 1.0199x over previous
//
#include <hip/hip_runtime.h>
#include <math.h>

// Problem constants (from reference)
#define BB 16
#define CC 3
#define OO 32
#define HH 128
#define WW 128
#define OH 124
#define OW 124
#define NPIX (OH * OW)          // 15376
#define NG   (NPIX / 4)         // 3844 4-pixel groups
#define GW   (OW / 4)           // 31 groups per output row
#define KF 25.0f

#define TPB  256
#define NBLK (NG / 4)           // 961 blocks, 16 pixels each (whole grid co-resident)

#if defined(__has_builtin)
#if __has_builtin(__builtin_amdgcn_sqrtf)
#define FSQRT(x) __builtin_amdgcn_sqrtf(x)
#else
#define FSQRT(x) sqrtf(x)
#endif
#else
#define FSQRT(x) sqrtf(x)
#endif

// exp(-0.5 z^2) = exp2(-(z*K2)^2), K2 = sqrt(0.5/ln2), folded into invstd
#define K2EXP 0.84932180f

// ---------------------------------------------------------------------------
// R10 structure, ONE change: plain f4 stores (no nontemporal) so L2 can merge
// the 64-B sibling half-lines (same XCD via swizzle) into full-line writebacks.
// Block owns 16 pixels x all (16 b, 32 o).
//   t = b*16 + og*4 + p4   (b: 0..15, og: 0..3 -> 8 o each, p4: 0..3)
// Phase 0: window sums from x -> LDS           (192 threads; t<96 preload W)
// Phase 1: dist partials, dist[8][4] in VGPRs  (256 threads)
// Phase 2: per-pixel unbiased 1/std (double)   (64 + 16 threads)
// Phase 3: out = exp2(-(d*isd')^2)             (256 threads, f4 stores)
// Bijective XCD swizzle (961 = 121 + 7*120); LDS rows padded to 17.
// ---------------------------------------------------------------------------
__global__ __launch_bounds__(TPB, 4)
void fused_one(const float* __restrict__ x,
               const float* __restrict__ wgt,
               float* __restrict__ out) {
    __shared__ float  sS1[BB * CC][17];    // 3.3 KB
    __shared__ float  sS2[BB * CC][17];    // 3.3 KB
    __shared__ float  sPS[BB * 4][17];     // 4.4 KB
    __shared__ float  sPQ[BB * 4][17];     // 4.4 KB
    __shared__ float  sW[OO * CC];
    __shared__ float  sInv[16];
    __shared__ double sRm[16][4];
    __shared__ double sRq[16][4];

    const int t = threadIdx.x;

    // Bijective XCD swizzle: round-robin dispatch puts orig%8 on XCD orig%8;
    // give each XCD a contiguous chunk range. 961 = 121 + 7*120.
    const int orig = blockIdx.x;
    const int xcd  = orig & 7;
    const int loc  = orig >> 3;
    const int chunk = ((xcd == 0) ? 0 : 121 + (xcd - 1) * 120) + loc;
    const int g0 = chunk * 4;              // first pix4 group of this block

    // ---------------- Phase 0: weights + window sums ----------------
    if (t < OO * CC) sW[t] = wgt[t];       // 96 weights
    if (t < BB * CC * 4) {                 // 192 active
        int bc = t >> 2;                   // 0..47
        int p4 = t & 3;                    // 0..3
        int g  = g0 + p4;
        int i  = g / GW;
        int j0 = (g % GW) * 4;
        const float* img = x + (size_t)bc * (HH * WW);
        float S1[4] = {0, 0, 0, 0}, S2[4] = {0, 0, 0, 0};
#pragma unroll
        for (int di = 0; di < 5; ++di) {
            const float4* rp = reinterpret_cast<const float4*>(img + (i + di) * WW + j0);
            float4 lo = rp[0], hi = rp[1];
            float v[8] = {lo.x, lo.y, lo.z, lo.w, hi.x, hi.y, hi.z, hi.w};
            float q[8];
#pragma unroll
            for (int k = 0; k < 8; ++k) q[k] = v[k] * v[k];
            float r  = v[0] + v[1] + v[2] + v[3] + v[4];
            float rq = q[0] + q[1] + q[2] + q[3] + q[4];
            S1[0] += r;  S2[0] += rq;
#pragma unroll
            for (int u = 1; u < 4; ++u) {
                r  += v[u + 4] - v[u - 1];
                rq += q[u + 4] - q[u - 1];
                S1[u] += r;  S2[u] += rq;
            }
        }
#pragma unroll
        for (int u = 0; u < 4; ++u) {
            sS1[bc][p4 * 4 + u] = S1[u];
            sS2[bc][p4 * 4 + u] = S2[u];
        }
    }
    __syncthreads();

    // ---------------- Phase 1: dist partials (dist stays in registers) ----
    const int b  = t >> 4;        // 0..15
    const int og = (t >> 2) & 3;  // 0..3  (8 o's each)
    const int p4 = t & 3;         // 0..3  (4 pixels each)

    float S1c[CC][4], S2c[CC][4];
#pragma unroll
    for (int c = 0; c < CC; ++c) {
#pragma unroll
        for (int u = 0; u < 4; ++u) {
            S1c[c][u] = sS1[b * CC + c][p4 * 4 + u];
            S2c[c][u] = sS2[b * CC + c][p4 * 4 + u];
        }
    }

    float dist[8][4];
    float sum[4] = {0, 0, 0, 0}, sq[4] = {0, 0, 0, 0};
#pragma unroll
    for (int oo = 0; oo < 8; ++oo) {
        int o = og * 8 + oo;
        float d[4] = {0, 0, 0, 0};
#pragma unroll
        for (int c = 0; c < CC; ++c) {
            float w  = sW[o * CC + c];
            float tw = 2.0f * w;
            float kw = KF * w * w;
#pragma unroll
            for (int u = 0; u < 4; ++u) {
                float inner = S2c[c][u] - tw * S1c[c][u] + kw;
                d[u] += FSQRT(fmaxf(inner, 0.0f));
            }
        }
#pragma unroll
        for (int u = 0; u < 4; ++u) {
            dist[oo][u] = d[u];
            sum[u] += d[u];
            sq[u]  += d[u] * d[u];
        }
    }
#pragma unroll
    for (int u = 0; u < 4; ++u) {
        sPS[b * 4 + og][p4 * 4 + u] = sum[u];
        sPQ[b * 4 + og][p4 * 4 + u] = sq[u];
    }
    __syncthreads();

    // ---------------- Phase 2: per-pixel 1/std (double) ----------------
    if (t < 64) {
        int pix = t >> 2;   // 0..15
        int seg = t & 3;    // 0..3, 16 rows each
        double sm = 0.0, sQ = 0.0;
#pragma unroll
        for (int k = 0; k < 16; ++k) {
            sm += (double)sPS[seg * 16 + k][pix];
            sQ += (double)sPQ[seg * 16 + k][pix];
        }
        sRm[pix][seg] = sm;
        sRq[pix][seg] = sQ;
    }
    __syncthreads();
    if (t < 16) {
        double sm = sRm[t][0] + sRm[t][1] + sRm[t][2] + sRm[t][3];
        double sQ = sRq[t][0] + sRq[t][1] + sRq[t][2] + sRq[t][3];
        const double n = (double)(BB * OO);
        double mean = sm / n;
        double var = (sQ - n * mean * mean) / (n - 1.0);
        if (var < 0.0) var = 0.0;
        // fold exp constant: exp(-0.5 z^2) = exp2(-(z*K2EXP)^2)
        sInv[t] = (float)(K2EXP / sqrt(var));
    }
    __syncthreads();

    // ---------------- Phase 3: output (plain f4 stores; L2 merges lines) --
    float isd[4];
#pragma unroll
    for (int u = 0; u < 4; ++u) isd[u] = sInv[p4 * 4 + u];
    const size_t pixbase = (size_t)(g0 + p4) * 4;

#pragma unroll
    for (int oo = 0; oo < 8; ++oo) {
        int o = og * 8 + oo;
        float4 r;
        float z0 = dist[oo][0] * isd[0]; r.x = exp2f(-(z0 * z0));
        float z1 = dist[oo][1] * isd[1]; r.y = exp2f(-(z1 * z1));
        float z2 = dist[oo][2] * isd[2]; r.z = exp2f(-(z2 * z2));
        float z3 = dist[oo][3] * isd[3]; r.w = exp2f(-(z3 * z3));
        *reinterpret_cast<float4*>(&out[(size_t)(b * OO + o) * NPIX + pixbase]) = r;
    }
}

// ---------------------------------------------------------------------------
extern "C" void kernel_launch(void* const* d_in, const int* in_sizes, int n_in,
                              void* d_out, int out_size, void* d_ws, size_t ws_size,
                              hipStream_t stream) {
    const float* x   = (const float*)d_in[0];   // (16,3,128,128)
    const float* wgt = (const float*)d_in[1];   // (32,3)
    float* out = (float*)d_out;                 // (16,32,124,124)

    fused_one<<<NBLK, TPB, 0, stream>>>(x, wgt, out);
}

// Round 14
// 18.013 us; speedup vs baseline: 1.0882x; 1.0669x over previous
//
#include <hip/hip_runtime.h>
#include <math.h>

// Problem constants (from reference)
#define BB 16
#define CC 3
#define OO 32
#define HH 128
#define WW 128
#define OH 124
#define OW 124
#define NPIX (OH * OW)          // 15376
#define NG   (NPIX / 4)         // 3844 4-pixel groups
#define GW   (OW / 4)           // 31 groups per output row
#define KF 25.0f

#define TPB  512
#define NBLK 481                // ceil(3844/8) chunks of 8 pix4 groups (32 pixels)

typedef float vfloat4 __attribute__((ext_vector_type(4)));  // native vec for nt-store

#if defined(__has_builtin)
#if __has_builtin(__builtin_amdgcn_sqrtf)
#define FSQRT(x) __builtin_amdgcn_sqrtf(x)
#else
#define FSQRT(x) sqrtf(x)
#endif
#else
#define FSQRT(x) sqrtf(x)
#endif

// exp(-0.5 z^2) = exp2(-(z*K2)^2), K2 = sqrt(0.5/ln2), folded into invstd
#define K2EXP 0.84932180f

// ---------------------------------------------------------------------------
// R11 structure, ONE change: nontemporal stores. Each wave-store covers
// 8 planes x 128 B contiguous = full HBM lines, bypassing L2 (no write-
// allocate pollution, no partial-line writes).
// Block owns 32 pixels (8 pix4 groups) x all (16 b, 32 o).
//   t = b*32 + og*8 + p4   (b: 0..15, og: 0..3 -> 8 o each, p4: 0..7)
// Phase 0: window sums from x -> LDS           (384 threads; t<96 preload W)
// Phase 1: dist partials, dist[8][4] in VGPRs  (512 threads)
// Phase 2: per-pixel unbiased 1/std (double)   (128 + 32 threads)
// Phase 3: out = exp2(-(d*isd')^2)             (512 threads, nt f4 stores)
// Bijective XCD swizzle (481 = 61 + 7*60). Tail block (chunk 480) guarded.
// ---------------------------------------------------------------------------
__global__ __launch_bounds__(TPB, 2)
void fused_one(const float* __restrict__ x,
               const float* __restrict__ wgt,
               float* __restrict__ out) {
    __shared__ float  sS1[BB * CC][33];    // 6.3 KB
    __shared__ float  sS2[BB * CC][33];    // 6.3 KB
    __shared__ float  sPS[BB * 4][33];     // 8.4 KB
    __shared__ float  sPQ[BB * 4][33];     // 8.4 KB
    __shared__ float  sW[OO * CC];
    __shared__ float  sInv[32];
    __shared__ double sRm[32][4];
    __shared__ double sRq[32][4];

    const int t = threadIdx.x;

    // Bijective XCD swizzle: 481 = 61 + 7*60 (xcd0 gets 61 chunks).
    const int orig = blockIdx.x;
    const int xcd  = orig & 7;
    const int loc  = orig >> 3;
    const int chunk = ((xcd == 0) ? 0 : 61 + (xcd - 1) * 60) + loc;
    const int g0 = chunk * 8;              // first pix4 group (8 per block)

    // ---------------- Phase 0: weights + window sums ----------------
    if (t < OO * CC) sW[t] = wgt[t];       // 96 weights
    if (t < BB * CC * 8) {                 // 384 active
        int bc = t >> 3;                   // 0..47
        int p4 = t & 7;                    // 0..7
        int g  = g0 + p4;
        if (g < NG) {
            int i  = g / GW;
            int j0 = (g % GW) * 4;
            const float* img = x + (size_t)bc * (HH * WW);
            float S1[4] = {0, 0, 0, 0}, S2[4] = {0, 0, 0, 0};
#pragma unroll
            for (int di = 0; di < 5; ++di) {
                const float4* rp = reinterpret_cast<const float4*>(img + (i + di) * WW + j0);
                float4 lo = rp[0], hi = rp[1];
                float v[8] = {lo.x, lo.y, lo.z, lo.w, hi.x, hi.y, hi.z, hi.w};
                float q[8];
#pragma unroll
                for (int k = 0; k < 8; ++k) q[k] = v[k] * v[k];
                float r  = v[0] + v[1] + v[2] + v[3] + v[4];
                float rq = q[0] + q[1] + q[2] + q[3] + q[4];
                S1[0] += r;  S2[0] += rq;
#pragma unroll
                for (int u = 1; u < 4; ++u) {
                    r  += v[u + 4] - v[u - 1];
                    rq += q[u + 4] - q[u - 1];
                    S1[u] += r;  S2[u] += rq;
                }
            }
#pragma unroll
            for (int u = 0; u < 4; ++u) {
                sS1[bc][p4 * 4 + u] = S1[u];
                sS2[bc][p4 * 4 + u] = S2[u];
            }
        } else {
#pragma unroll
            for (int u = 0; u < 4; ++u) {
                sS1[bc][p4 * 4 + u] = 0.0f;
                sS2[bc][p4 * 4 + u] = 0.0f;
            }
        }
    }
    __syncthreads();

    // ---------------- Phase 1: dist partials (dist stays in registers) ----
    const int b  = t >> 5;        // 0..15
    const int og = (t >> 3) & 3;  // 0..3  (8 o's each)
    const int p4 = t & 7;         // 0..7  (4 pixels each)

    float S1c[CC][4], S2c[CC][4];
#pragma unroll
    for (int c = 0; c < CC; ++c) {
#pragma unroll
        for (int u = 0; u < 4; ++u) {
            S1c[c][u] = sS1[b * CC + c][p4 * 4 + u];
            S2c[c][u] = sS2[b * CC + c][p4 * 4 + u];
        }
    }

    float dist[8][4];
    float sum[4] = {0, 0, 0, 0}, sq[4] = {0, 0, 0, 0};
#pragma unroll
    for (int oo = 0; oo < 8; ++oo) {
        int o = og * 8 + oo;
        float d[4] = {0, 0, 0, 0};
#pragma unroll
        for (int c = 0; c < CC; ++c) {
            float w  = sW[o * CC + c];
            float tw = 2.0f * w;
            float kw = KF * w * w;
#pragma unroll
            for (int u = 0; u < 4; ++u) {
                float inner = S2c[c][u] - tw * S1c[c][u] + kw;
                d[u] += FSQRT(fmaxf(inner, 0.0f));
            }
        }
#pragma unroll
        for (int u = 0; u < 4; ++u) {
            dist[oo][u] = d[u];
            sum[u] += d[u];
            sq[u]  += d[u] * d[u];
        }
    }
#pragma unroll
    for (int u = 0; u < 4; ++u) {
        sPS[b * 4 + og][p4 * 4 + u] = sum[u];
        sPQ[b * 4 + og][p4 * 4 + u] = sq[u];
    }
    __syncthreads();

    // ---------------- Phase 2: per-pixel 1/std (double) ----------------
    if (t < 128) {
        int pix = t >> 2;   // 0..31
        int seg = t & 3;    // 0..3, 16 rows each
        double sm = 0.0, sQ = 0.0;
#pragma unroll
        for (int k = 0; k < 16; ++k) {
            sm += (double)sPS[seg * 16 + k][pix];
            sQ += (double)sPQ[seg * 16 + k][pix];
        }
        sRm[pix][seg] = sm;
        sRq[pix][seg] = sQ;
    }
    __syncthreads();
    if (t < 32) {
        double sm = sRm[t][0] + sRm[t][1] + sRm[t][2] + sRm[t][3];
        double sQ = sRq[t][0] + sRq[t][1] + sRq[t][2] + sRq[t][3];
        const double n = (double)(BB * OO);
        double mean = sm / n;
        double var = (sQ - n * mean * mean) / (n - 1.0);
        if (var < 0.0) var = 0.0;
        // fold exp constant: exp(-0.5 z^2) = exp2(-(z*K2EXP)^2)
        sInv[t] = (float)(K2EXP / sqrt(var));
    }
    __syncthreads();

    // ---------------- Phase 3: output (nontemporal full-line stores) ------
    float isd[4];
#pragma unroll
    for (int u = 0; u < 4; ++u) isd[u] = sInv[p4 * 4 + u];
    const bool valid = (g0 + p4) < NG;
    const size_t pixbase = (size_t)(g0 + p4) * 4;

#pragma unroll
    for (int oo = 0; oo < 8; ++oo) {
        int o = og * 8 + oo;
        vfloat4 r;
        float z0 = dist[oo][0] * isd[0]; r.x = exp2f(-(z0 * z0));
        float z1 = dist[oo][1] * isd[1]; r.y = exp2f(-(z1 * z1));
        float z2 = dist[oo][2] * isd[2]; r.z = exp2f(-(z2 * z2));
        float z3 = dist[oo][3] * isd[3]; r.w = exp2f(-(z3 * z3));
        if (valid) {
            __builtin_nontemporal_store(r,
                reinterpret_cast<vfloat4*>(&out[(size_t)(b * OO + o) * NPIX + pixbase]));
        }
    }
}

// ---------------------------------------------------------------------------
extern "C" void kernel_launch(void* const* d_in, const int* in_sizes, int n_in,
                              void* d_out, int out_size, void* d_ws, size_t ws_size,
                              hipStream_t stream) {
    const float* x   = (const float*)d_in[0];   // (16,3,128,128)
    const float* wgt = (const float*)d_in[1];   // (32,3)
    float* out = (float*)d_out;                 // (16,32,124,124)

    fused_one<<<NBLK, TPB, 0, stream>>>(x, wgt, out);
}